// Round 7
// baseline (278.519 us; speedup 1.0000x reference)
//
#include <hip/hip_runtime.h>

#define HW 16384

typedef short bf16x8 __attribute__((ext_vector_type(8)));
typedef float f32x4 __attribute__((ext_vector_type(4)));

// output offsets (floats): cls_score, cls_score_neg, distances, distances_neg, probs_ori
static constexpr size_t OFF0 = 0;
static constexpr size_t OFF1 = 10616832;   // 8*81*16384
static constexpr size_t OFF2 = 21233664;
static constexpr size_t OFF3 = 31850496;
static constexpr size_t OFF4 = 63700992;   // OFF3 + 3*10616832

#define STG_STRIDE 264                      // floats, per staged map row (256 px + pad)

static __device__ __forceinline__ unsigned short f2bf(float f) {
  unsigned int u = __float_as_uint(f);
  u += 0x7fffu + ((u >> 16) & 1u);   // RNE
  return (unsigned short)(u >> 16);
}

// write one (row R, channel j) bf16 value into the MFMA A-frag layout
static __device__ __forceinline__ void frag_write(unsigned short* wsA, int R, int j,
                                                  unsigned short v) {
  const int mt = R >> 4;
  const int ks = j >> 5;
  const int hi = (j >> 3) & 3;
  const int jj = j & 7;
  const int lane = hi * 16 + (R & 15);
  wsA[((size_t)((mt * 4 + ks) * 64 + lane)) * 8 + jj] = v;
}

// ===== PROBE: 4KB-run scatter write of all 297MB, candidate px-1024 pattern =====
// 256 blocks: n = b>>5, chunk = (b>>1)&15 (1024 px), half = b&1 (o-range).
// One store instruction = one full 4KB run of one map (256 lanes x 16B); two maps
// covered per instruction by the 512-thread block.
__global__ __launch_bounds__(512) void probe_scatter4k(float* __restrict__ out) {
  const int b = blockIdx.x;
  const int n = b >> 5;
  const int chunk = (b >> 1) & 15;
  const int half = b & 1;
  const int p0 = chunk << 10;
  const int o0 = half ? 40 : 0;
  const int nmaps = (half ? 41 : 40) * 7;
  const int t = threadIdx.x;
  const int px4 = (t & 255) * 4;
  const f32x4 v = {1.f, 2.f, 3.f, 4.f};
  for (int m = 0; m < nmaps; m += 2) {
    const int mi = m + (t >> 8);
    if (mi < nmaps) {
      const int o = o0 + mi / 7;
      const int jv = mi % 7;
      const size_t idx81 = (size_t)(n * 81 + o);
      size_t off;
      if (jv == 0) off = OFF2 + idx81 * HW;
      else if (jv <= 3) off = OFF3 + (idx81 * 3 + (jv - 1)) * HW;
      else if (jv == 4) off = OFF1 + idx81 * HW;
      else if (jv == 5) off = OFF4 + idx81 * HW;
      else off = OFF0 + idx81 * HW;
      __builtin_nontemporal_store(v, (f32x4*)(out + off + p0 + px4));
    }
  }
}

// ---------------- fused prep: reps + full 3-stage chain + norm + frag pack ----------------
__global__ __launch_bounds__(128) void prep_all(const float* __restrict__ rw,
                                                const float* __restrict__ rb,
                                                const float* __restrict__ nw,
                                                const float* __restrict__ nb,
                                                unsigned short* __restrict__ wsA) {
  const int b = blockIdx.x;
  const int k = b / 81, o = b % 81;
  const int j = threadIdx.x;
  __shared__ __align__(16) float hrow[128];
  __shared__ float red[2];

  float v = rw[o * 128 + j] + rb[o * 128 + j];
  float sq = v * v;
#pragma unroll
  for (int m = 1; m < 64; m <<= 1) sq += __shfl_xor(sq, m, 64);
  if ((j & 63) == 0) red[j >> 6] = sq;
  __syncthreads();
  const float r = v / fmaxf(sqrtf(red[0] + red[1]), 1e-12f);
  __syncthreads();
  hrow[j] = r;
  __syncthreads();

  float acc = 0.f;
#pragma unroll
  for (int l = 0; l < 3; ++l) {
    const float4* Wr = (const float4*)(nw + (((size_t)(k * 3 + l)) * 128 + j) * 128);
    const float4* H  = (const float4*)hrow;
    float4 a = {0.f, 0.f, 0.f, 0.f};
#pragma unroll
    for (int q = 0; q < 32; ++q) {
      float4 wv = Wr[q]; float4 hv = H[q];
      a.x = fmaf(wv.x, hv.x, a.x); a.y = fmaf(wv.y, hv.y, a.y);
      a.z = fmaf(wv.z, hv.z, a.z); a.w = fmaf(wv.w, hv.w, a.w);
    }
    acc = (a.x + a.y) + (a.z + a.w) + nb[(k * 3 + l) * 128 + j];
    if (l < 2) acc = fmaxf(acc, 0.f);
    __syncthreads();
    if (l < 2) hrow[j] = acc;
    __syncthreads();
  }

  float sq2 = acc * acc;
#pragma unroll
  for (int m = 1; m < 64; m <<= 1) sq2 += __shfl_xor(sq2, m, 64);
  if ((j & 63) == 0) red[j >> 6] = sq2;
  __syncthreads();
  const float accn = acc / fmaxf(sqrtf(red[0] + red[1]), 1e-12f);

  frag_write(wsA, o * 4 + k + 1, j, f2bf(accn));
  if (k == 0) frag_write(wsA, o * 4, j, f2bf(r));
  if (b == 0) {
#pragma unroll
    for (int R = 324; R < 336; ++R) frag_write(wsA, R, j, (unsigned short)0);
  }
}

// ---------------- main: 256-px tile, LDS-staged 1KB-per-map cooperative writeout ----------
__global__ __launch_bounds__(512, 4) void main_kernel(const float* __restrict__ x,
                                                      const bf16x8* __restrict__ wsA,
                                                      float* __restrict__ out) {
  __shared__ __align__(16) char lds[74752];
  float* ss   = (float*)(lds + 65536);
  float* invn = (float*)(lds + 73728);
  float* stg  = (float*)lds;

  const int b = blockIdx.x;
  const int n = b >> 6;
  const int p0 = (b & 63) << 8;      // 256-px chunk
  const int t = threadIdx.x;
  const int lane = t & 63;
  const int w = t >> 6;
  const float* xb = x + ((size_t)n * 128) * HW + p0;

  {
    const int pq = (t & 63) * 4;
    const int swz = (t & 7) << 4;
    float a0 = 0.f, a1 = 0.f, a2 = 0.f, a3 = 0.f;
#pragma unroll
    for (int i = 0; i < 4; ++i) {
      const int c0 = i * 32 + w * 4;
      float4 v0 = *(const float4*)(xb + (size_t)(c0 + 0) * HW + pq);
      float4 v1 = *(const float4*)(xb + (size_t)(c0 + 1) * HW + pq);
      float4 v2 = *(const float4*)(xb + (size_t)(c0 + 2) * HW + pq);
      float4 v3 = *(const float4*)(xb + (size_t)(c0 + 3) * HW + pq);
      a0 = fmaf(v0.x, v0.x, fmaf(v1.x, v1.x, fmaf(v2.x, v2.x, fmaf(v3.x, v3.x, a0))));
      a1 = fmaf(v0.y, v0.y, fmaf(v1.y, v1.y, fmaf(v2.y, v2.y, fmaf(v3.y, v3.y, a1))));
      a2 = fmaf(v0.z, v0.z, fmaf(v1.z, v1.z, fmaf(v2.z, v2.z, fmaf(v3.z, v3.z, a2))));
      a3 = fmaf(v0.w, v0.w, fmaf(v1.w, v1.w, fmaf(v2.w, v2.w, fmaf(v3.w, v3.w, a3))));
      uint2 wd;
      wd.x = (unsigned)f2bf(v0.x) | ((unsigned)f2bf(v1.x) << 16);
      wd.y = (unsigned)f2bf(v2.x) | ((unsigned)f2bf(v3.x) << 16);
      *(uint2*)(lds + (((pq + 0) * 256 + c0 * 2) ^ swz)) = wd;
      wd.x = (unsigned)f2bf(v0.y) | ((unsigned)f2bf(v1.y) << 16);
      wd.y = (unsigned)f2bf(v2.y) | ((unsigned)f2bf(v3.y) << 16);
      *(uint2*)(lds + (((pq + 1) * 256 + c0 * 2) ^ swz)) = wd;
      wd.x = (unsigned)f2bf(v0.z) | ((unsigned)f2bf(v1.z) << 16);
      wd.y = (unsigned)f2bf(v2.z) | ((unsigned)f2bf(v3.z) << 16);
      *(uint2*)(lds + (((pq + 2) * 256 + c0 * 2) ^ swz)) = wd;
      wd.x = (unsigned)f2bf(v0.w) | ((unsigned)f2bf(v1.w) << 16);
      wd.y = (unsigned)f2bf(v2.w) | ((unsigned)f2bf(v3.w) << 16);
      *(uint2*)(lds + (((pq + 3) * 256 + c0 * 2) ^ swz)) = wd;
    }
    float4 st = {a0, a1, a2, a3};
    *(float4*)&ss[w * 256 + pq] = st;
  }
  __syncthreads();
  if (t < 256) {
    float s = 0.f;
#pragma unroll
    for (int g = 0; g < 8; ++g) s += ss[g * 256 + t];
    invn[t] = __builtin_amdgcn_rsqf(fmaxf(s, 1e-24f));
  }
  __syncthreads();

  const int og = lane >> 4;
  const int px16 = lane & 15;

  bf16x8 bfrag[2][4];
  float ivp[2];
#pragma unroll
  for (int u = 0; u < 2; ++u) {
    const int p = w * 32 + u * 16 + px16;
    const int swzr = ((p >> 2) & 7) << 4;
#pragma unroll
    for (int ks = 0; ks < 4; ++ks) {
      const int addr = (p * 256 + ks * 64 + (lane >> 4) * 16) ^ swzr;
      bfrag[u][ks] = *(const bf16x8*)(lds + addr);
    }
    ivp[u] = invn[p];
  }
  __syncthreads();

  unsigned probs_pk[21];

#pragma unroll
  for (int mt = 0; mt < 21; ++mt) {
    bf16x8 afr[4];
#pragma unroll
    for (int ks = 0; ks < 4; ++ks) afr[ks] = wsA[(mt * 4 + ks) * 64 + lane];
    f32x4 c0 = {0.f, 0.f, 0.f, 0.f}, c1 = {0.f, 0.f, 0.f, 0.f};
#pragma unroll
    for (int ks = 0; ks < 4; ++ks) {
      c0 = __builtin_amdgcn_mfma_f32_16x16x32_bf16(afr[ks], bfrag[0][ks], c0, 0, 0, 0);
      c1 = __builtin_amdgcn_mfma_f32_16x16x32_bf16(afr[ks], bfrag[1][ks], c1, 0, 0, 0);
    }
    const int o = mt * 4 + og;
    const bool valid = (o < 81);
    float pru[2];
#pragma unroll
    for (int u = 0; u < 2; ++u) {
      const f32x4 c = u ? c1 : c0;
      const float iv = ivp[u];
      float q0 = fmaxf(2.f - 2.f * (c[0] * iv), 0.f);
      float q1 = fmaxf(2.f - 2.f * (c[1] * iv), 0.f);
      float q2 = fmaxf(2.f - 2.f * (c[2] * iv), 0.f);
      float q3 = fmaxf(2.f - 2.f * (c[3] * iv), 0.f);
      float d0 = __builtin_amdgcn_sqrtf(q0);
      float d1 = __builtin_amdgcn_sqrtf(q1);
      float d2 = __builtin_amdgcn_sqrtf(q2);
      float d3 = __builtin_amdgcn_sqrtf(q3);
      float qmin = fminf(q1, fminf(q2, q3));
      float dmin = fminf(d1, fminf(d2, d3));
      float pneg = __expf(-2.f * qmin);
      float pori = __expf(-2.f * q0);
      float tt = d0 + 0.3f * fmaxf(2.f - dmin, 0.f);
      float pr = __expf(-2.f * tt * tt);
      pru[u] = valid ? pr : 0.f;
      float* su = stg + og * 6 * STG_STRIDE + w * 32 + u * 16 + px16;
      su[0] = d0;
      su[1 * STG_STRIDE] = d1;
      su[2 * STG_STRIDE] = d2;
      su[3 * STG_STRIDE] = d3;
      su[4 * STG_STRIDE] = pneg;
      su[5 * STG_STRIDE] = pori;
    }
    probs_pk[mt] = ((unsigned)f2bf(pru[1]) << 16) | (unsigned)f2bf(pru[0]);
    __syncthreads();
#pragma unroll
    for (int r = 0; r < 3; ++r) {
      const int m = w * 3 + r;
      const int ogm = m / 6, jv = m % 6;
      const int oo = mt * 4 + ogm;
      f32x4 v = *(const f32x4*)(stg + m * STG_STRIDE + lane * 4);
      if (oo < 81) {
        const size_t idx81 = (size_t)(n * 81 + oo);
        size_t off;
        if (jv == 0) off = OFF2 + idx81 * HW;
        else if (jv <= 3) off = OFF3 + (idx81 * 3 + (jv - 1)) * HW;
        else if (jv == 4) off = OFF1 + idx81 * HW;
        else off = OFF4 + idx81 * HW;
        __builtin_nontemporal_store(v, (f32x4*)(out + off + p0 + lane * 4));
      }
    }
    __syncthreads();
  }

  float s0 = 0.f, s1 = 0.f;
#pragma unroll
  for (int mt = 0; mt < 21; ++mt) {
    s0 += __uint_as_float(probs_pk[mt] << 16);
    s1 += __uint_as_float(probs_pk[mt] & 0xffff0000u);
  }
  s0 += __shfl_xor(s0, 16, 64); s0 += __shfl_xor(s0, 32, 64);
  s1 += __shfl_xor(s1, 16, 64); s1 += __shfl_xor(s1, 32, 64);
  const float is0 = __builtin_amdgcn_rcpf(s0);
  const float is1 = __builtin_amdgcn_rcpf(s1);

#pragma unroll
  for (int g = 0; g < 4; ++g) {
    const int nj = (g < 3) ? 6 : 3;
#pragma unroll
    for (int j = 0; j < 6; ++j) {
      if (j < nj) {
        const int mt = g * 6 + j;
        const float v0 = __uint_as_float(probs_pk[mt] << 16) * is0;
        const float v1 = __uint_as_float(probs_pk[mt] & 0xffff0000u) * is1;
        float* su = stg + (j * 4 + og) * STG_STRIDE + w * 32 + px16;
        su[0] = v0;
        su[16] = v1;
      }
    }
    __syncthreads();
    const int nrows = nj * 4;
#pragma unroll
    for (int r = 0; r < 3; ++r) {
      const int m = w * 3 + r;
      if (m < nrows) {
        const int j = m >> 2, ogm = m & 3;
        const int oo = (g * 6 + j) * 4 + ogm;
        f32x4 v = *(const f32x4*)(stg + m * STG_STRIDE + lane * 4);
        if (oo < 81) {
          __builtin_nontemporal_store(
              v, (f32x4*)(out + OFF0 + (size_t)(n * 81 + oo) * HW + p0 + lane * 4));
        }
      }
    }
    __syncthreads();
  }
}

extern "C" void kernel_launch(void* const* d_in, const int* in_sizes, int n_in,
                              void* d_out, int out_size, void* d_ws, size_t ws_size,
                              hipStream_t stream) {
  const float* x  = (const float*)d_in[0];
  const float* rw = (const float*)d_in[1];
  const float* rb = (const float*)d_in[2];
  const float* nw = (const float*)d_in[3];
  const float* nb = (const float*)d_in[4];
  float* out = (float*)d_out;
  unsigned short* wsA_us = (unsigned short*)d_ws;
  const bf16x8* wsA = (const bf16x8*)d_ws;

  // PROBE ROUND 2: 4KB-run scatter pattern x3; fully overwritten by main_kernel.
  hipLaunchKernelGGL(probe_scatter4k, dim3(256), dim3(512), 0, stream, out);
  hipLaunchKernelGGL(probe_scatter4k, dim3(256), dim3(512), 0, stream, out);
  hipLaunchKernelGGL(probe_scatter4k, dim3(256), dim3(512), 0, stream, out);
  hipLaunchKernelGGL(prep_all, dim3(243), dim3(128), 0, stream, rw, rb, nw, nb, wsA_us);
  hipLaunchKernelGGL(main_kernel, dim3(512), dim3(512), 0, stream, x, wsA, out);
}

// Round 8
// 108.931 us; speedup vs baseline: 2.5568x; 2.5568x over previous
//
#include <hip/hip_runtime.h>

#define HW 16384

typedef short bf16x8 __attribute__((ext_vector_type(8)));
typedef float f32x4 __attribute__((ext_vector_type(4)));

// output offsets (floats): cls_score, cls_score_neg, distances, distances_neg, probs_ori
static constexpr size_t OFF0 = 0;
static constexpr size_t OFF1 = 10616832;   // 8*81*16384
static constexpr size_t OFF2 = 21233664;
static constexpr size_t OFF3 = 31850496;
static constexpr size_t OFF4 = 63700992;   // OFF3 + 3*10616832

#define STRIDE 520                          // floats per staged map row (512 px + 8 pad)

static __device__ __forceinline__ unsigned short f2bf(float f) {
  unsigned int u = __float_as_uint(f);
  u += 0x7fffu + ((u >> 16) & 1u);   // RNE
  return (unsigned short)(u >> 16);
}

static __device__ __forceinline__ float bflo(unsigned pk) {
  return __uint_as_float(pk << 16);
}
static __device__ __forceinline__ float bfhi(unsigned pk) {
  return __uint_as_float(pk & 0xffff0000u);
}

// write one (row R, channel j) bf16 value into the MFMA A-frag layout
static __device__ __forceinline__ void frag_write(unsigned short* wsA, int R, int j,
                                                  unsigned short v) {
  const int mt = R >> 4;
  const int ks = j >> 5;
  const int hi = (j >> 3) & 3;
  const int jj = j & 7;
  const int lane = hi * 16 + (R & 15);
  wsA[((size_t)((mt * 4 + ks) * 64 + lane)) * 8 + jj] = v;
}

// ---------------- fused prep: reps + full 3-stage chain + norm + frag pack ----------------
__global__ __launch_bounds__(128) void prep_all(const float* __restrict__ rw,
                                                const float* __restrict__ rb,
                                                const float* __restrict__ nw,
                                                const float* __restrict__ nb,
                                                unsigned short* __restrict__ wsA) {
  const int b = blockIdx.x;
  const int k = b / 81, o = b % 81;
  const int j = threadIdx.x;
  __shared__ __align__(16) float hrow[128];
  __shared__ float red[2];

  float v = rw[o * 128 + j] + rb[o * 128 + j];
  float sq = v * v;
#pragma unroll
  for (int m = 1; m < 64; m <<= 1) sq += __shfl_xor(sq, m, 64);
  if ((j & 63) == 0) red[j >> 6] = sq;
  __syncthreads();
  const float r = v / fmaxf(sqrtf(red[0] + red[1]), 1e-12f);
  __syncthreads();
  hrow[j] = r;
  __syncthreads();

  float acc = 0.f;
#pragma unroll
  for (int l = 0; l < 3; ++l) {
    const float4* Wr = (const float4*)(nw + (((size_t)(k * 3 + l)) * 128 + j) * 128);
    const float4* H  = (const float4*)hrow;
    float4 a = {0.f, 0.f, 0.f, 0.f};
#pragma unroll
    for (int q = 0; q < 32; ++q) {
      float4 wv = Wr[q]; float4 hv = H[q];
      a.x = fmaf(wv.x, hv.x, a.x); a.y = fmaf(wv.y, hv.y, a.y);
      a.z = fmaf(wv.z, hv.z, a.z); a.w = fmaf(wv.w, hv.w, a.w);
    }
    acc = (a.x + a.y) + (a.z + a.w) + nb[(k * 3 + l) * 128 + j];
    if (l < 2) acc = fmaxf(acc, 0.f);
    __syncthreads();
    if (l < 2) hrow[j] = acc;
    __syncthreads();
  }

  float sq2 = acc * acc;
#pragma unroll
  for (int m = 1; m < 64; m <<= 1) sq2 += __shfl_xor(sq2, m, 64);
  if ((j & 63) == 0) red[j >> 6] = sq2;
  __syncthreads();
  const float accn = acc / fmaxf(sqrtf(red[0] + red[1]), 1e-12f);

  frag_write(wsA, o * 4 + k + 1, j, f2bf(accn));
  if (k == 0) frag_write(wsA, o * 4, j, f2bf(r));
  if (b == 0) {
#pragma unroll
    for (int R = 324; R < 336; ++R) frag_write(wsA, R, j, (unsigned short)0);
  }
}

// ---------------- main: 512-px tile, all-o, 2KB-run LDS-staged writeout ----------------
// LDS: [0,131072) E tile (512px x 128ch bf16, swizzled) -> reused as staging
//      [131072,139264) ss[4][512]   [139264,141312) invn[512]
__global__ __launch_bounds__(512) void main_kernel(const float* __restrict__ x,
                                                   const bf16x8* __restrict__ wsA,
                                                   float* __restrict__ out) {
  __shared__ __align__(16) char lds[141312];
  float* ss   = (float*)(lds + 131072);
  float* invn = (float*)(lds + 139264);
  float* stg  = (float*)lds;

  const int b = blockIdx.x;
  const int n = b >> 5;
  const int p0 = (b & 31) << 9;      // 512-px chunk
  const int t = threadIdx.x;
  const int lane = t & 63;
  const int w = t >> 6;              // wave 0..7, owns local px [w*64, w*64+64)
  const float* xb = x + ((size_t)n * 128) * HW + p0;

  // ---- build E tile: thread covers px-quad (t&127), channel group (t>>7) ----
  {
    const int pq = (t & 127) * 4;
    const int cg = t >> 7;           // 0..3
    const int swz = (t & 7) << 4;    // ((px>>2)&7)<<4
    float a0 = 0.f, a1 = 0.f, a2 = 0.f, a3 = 0.f;
#pragma unroll
    for (int i = 0; i < 8; ++i) {
      const int c0 = i * 16 + cg * 4;
      float4 v0 = *(const float4*)(xb + (size_t)(c0 + 0) * HW + pq);
      float4 v1 = *(const float4*)(xb + (size_t)(c0 + 1) * HW + pq);
      float4 v2 = *(const float4*)(xb + (size_t)(c0 + 2) * HW + pq);
      float4 v3 = *(const float4*)(xb + (size_t)(c0 + 3) * HW + pq);
      a0 = fmaf(v0.x, v0.x, fmaf(v1.x, v1.x, fmaf(v2.x, v2.x, fmaf(v3.x, v3.x, a0))));
      a1 = fmaf(v0.y, v0.y, fmaf(v1.y, v1.y, fmaf(v2.y, v2.y, fmaf(v3.y, v3.y, a1))));
      a2 = fmaf(v0.z, v0.z, fmaf(v1.z, v1.z, fmaf(v2.z, v2.z, fmaf(v3.z, v3.z, a2))));
      a3 = fmaf(v0.w, v0.w, fmaf(v1.w, v1.w, fmaf(v2.w, v2.w, fmaf(v3.w, v3.w, a3))));
      uint2 wd;
      wd.x = (unsigned)f2bf(v0.x) | ((unsigned)f2bf(v1.x) << 16);
      wd.y = (unsigned)f2bf(v2.x) | ((unsigned)f2bf(v3.x) << 16);
      *(uint2*)(lds + (((pq + 0) * 256 + c0 * 2) ^ swz)) = wd;
      wd.x = (unsigned)f2bf(v0.y) | ((unsigned)f2bf(v1.y) << 16);
      wd.y = (unsigned)f2bf(v2.y) | ((unsigned)f2bf(v3.y) << 16);
      *(uint2*)(lds + (((pq + 1) * 256 + c0 * 2) ^ swz)) = wd;
      wd.x = (unsigned)f2bf(v0.z) | ((unsigned)f2bf(v1.z) << 16);
      wd.y = (unsigned)f2bf(v2.z) | ((unsigned)f2bf(v3.z) << 16);
      *(uint2*)(lds + (((pq + 2) * 256 + c0 * 2) ^ swz)) = wd;
      wd.x = (unsigned)f2bf(v0.w) | ((unsigned)f2bf(v1.w) << 16);
      wd.y = (unsigned)f2bf(v2.w) | ((unsigned)f2bf(v3.w) << 16);
      *(uint2*)(lds + (((pq + 3) * 256 + c0 * 2) ^ swz)) = wd;
    }
    float4 st = {a0, a1, a2, a3};
    *(float4*)&ss[cg * 512 + pq] = st;
  }
  __syncthreads();
  {
    float s = ss[t] + ss[512 + t] + ss[1024 + t] + ss[1536 + t];
    invn[t] = __builtin_amdgcn_rsqf(fmaxf(s, 1e-24f));
  }
  __syncthreads();

  const int og = lane >> 4;
  const int px16 = lane & 15;

  // ---- B-fragments: 4 u-slots (64 px per wave), 64 VGPR ----
  bf16x8 bfrag[4][4];
  float ivp[4];
#pragma unroll
  for (int u = 0; u < 4; ++u) {
    const int p = w * 64 + u * 16 + px16;
    const int swzr = ((p >> 2) & 7) << 4;
#pragma unroll
    for (int ks = 0; ks < 4; ++ks) {
      const int addr = (p * 256 + ks * 64 + (lane >> 4) * 16) ^ swzr;
      bfrag[u][ks] = *(const bf16x8*)(lds + addr);
    }
    ivp[u] = invn[p];
  }
  __syncthreads();   // E consumed; stg region reusable

  unsigned p01[21], p23[21];

#pragma unroll
  for (int mt = 0; mt < 21; ++mt) {
    bf16x8 afr[4];
#pragma unroll
    for (int ks = 0; ks < 4; ++ks) afr[ks] = wsA[(mt * 4 + ks) * 64 + lane];
    f32x4 cc[4];
#pragma unroll
    for (int u = 0; u < 4; ++u) cc[u] = (f32x4){0.f, 0.f, 0.f, 0.f};
#pragma unroll
    for (int ks = 0; ks < 4; ++ks) {
#pragma unroll
      for (int u = 0; u < 4; ++u)
        cc[u] = __builtin_amdgcn_mfma_f32_16x16x32_bf16(afr[ks], bfrag[u][ks], cc[u], 0, 0, 0);
    }
    const int o = mt * 4 + og;
    const bool valid = (o < 81);
    float pr_[4];
#pragma unroll
    for (int u = 0; u < 4; ++u) {
      const f32x4 c = cc[u];
      const float iv = ivp[u];
      float q0 = fmaxf(2.f - 2.f * (c[0] * iv), 0.f);
      float q1 = fmaxf(2.f - 2.f * (c[1] * iv), 0.f);
      float q2 = fmaxf(2.f - 2.f * (c[2] * iv), 0.f);
      float q3 = fmaxf(2.f - 2.f * (c[3] * iv), 0.f);
      float d0 = __builtin_amdgcn_sqrtf(q0);
      float d1 = __builtin_amdgcn_sqrtf(q1);
      float d2 = __builtin_amdgcn_sqrtf(q2);
      float d3 = __builtin_amdgcn_sqrtf(q3);
      float qmin = fminf(q1, fminf(q2, q3));
      float dmin = fminf(d1, fminf(d2, d3));
      float pneg = __expf(-2.f * qmin);
      float pori = __expf(-2.f * q0);
      float tt = d0 + 0.3f * fmaxf(2.f - dmin, 0.f);
      float pr = __expf(-2.f * tt * tt);
      pr_[u] = valid ? pr : 0.f;
      float* su = stg + og * 6 * STRIDE + w * 64 + u * 16 + px16;
      su[0 * STRIDE] = d0;
      su[1 * STRIDE] = d1;
      su[2 * STRIDE] = d2;
      su[3 * STRIDE] = d3;
      su[4 * STRIDE] = pneg;
      su[5 * STRIDE] = pori;
    }
    p01[mt] = ((unsigned)f2bf(pr_[1]) << 16) | (unsigned)f2bf(pr_[0]);
    p23[mt] = ((unsigned)f2bf(pr_[3]) << 16) | (unsigned)f2bf(pr_[2]);
    __syncthreads();
    // writeout: wave owns 3 maps; per map, 2 back-to-back f32x4 = monotone 2KB run
#pragma unroll
    for (int r = 0; r < 3; ++r) {
      const int m = w * 3 + r;          // 0..23
      const int ogm = m / 6, jv = m % 6;
      const int oo = mt * 4 + ogm;
      f32x4 h0 = *(const f32x4*)(stg + m * STRIDE + lane * 4);
      f32x4 h1 = *(const f32x4*)(stg + m * STRIDE + 256 + lane * 4);
      if (oo < 81) {
        const size_t idx81 = (size_t)(n * 81 + oo);
        size_t off;
        if (jv == 0) off = OFF2 + idx81 * HW;
        else if (jv <= 3) off = OFF3 + (idx81 * 3 + (jv - 1)) * HW;
        else if (jv == 4) off = OFF1 + idx81 * HW;
        else off = OFF4 + idx81 * HW;
        __builtin_nontemporal_store(h0, (f32x4*)(out + off + p0 + lane * 4));
        __builtin_nontemporal_store(h1, (f32x4*)(out + off + p0 + 256 + lane * 4));
      }
    }
    __syncthreads();
  }

  // ---- cls_score: per-px sum over all o (in-lane over mt, shfl over og) ----
  float s0 = 0.f, s1 = 0.f, s2 = 0.f, s3 = 0.f;
#pragma unroll
  for (int mt = 0; mt < 21; ++mt) {
    s0 += bflo(p01[mt]); s1 += bfhi(p01[mt]);
    s2 += bflo(p23[mt]); s3 += bfhi(p23[mt]);
  }
  s0 += __shfl_xor(s0, 16, 64); s0 += __shfl_xor(s0, 32, 64);
  s1 += __shfl_xor(s1, 16, 64); s1 += __shfl_xor(s1, 32, 64);
  s2 += __shfl_xor(s2, 16, 64); s2 += __shfl_xor(s2, 32, 64);
  s3 += __shfl_xor(s3, 16, 64); s3 += __shfl_xor(s3, 32, 64);
  const float is0 = __builtin_amdgcn_rcpf(s0);
  const float is1 = __builtin_amdgcn_rcpf(s1);
  const float is2 = __builtin_amdgcn_rcpf(s2);
  const float is3 = __builtin_amdgcn_rcpf(s3);

#pragma unroll
  for (int g = 0; g < 6; ++g) {
    const int nmt = (g < 5) ? 4 : 1;
#pragma unroll
    for (int mtl = 0; mtl < 4; ++mtl) {
      if (mtl < nmt) {
        const int mt = g * 4 + mtl;
        float* su = stg + (mtl * 4 + og) * STRIDE + w * 64 + px16;
        su[0]  = bflo(p01[mt]) * is0;
        su[16] = bfhi(p01[mt]) * is1;
        su[32] = bflo(p23[mt]) * is2;
        su[48] = bfhi(p23[mt]) * is3;
      }
    }
    __syncthreads();
    const int nrows = nmt * 4;
#pragma unroll
    for (int r = 0; r < 2; ++r) {
      const int m = w * 2 + r;          // 0..15
      if (m < nrows) {
        const int mtl = m >> 2, ogm = m & 3;
        const int oo = (g * 4 + mtl) * 4 + ogm;
        f32x4 h0 = *(const f32x4*)(stg + m * STRIDE + lane * 4);
        f32x4 h1 = *(const f32x4*)(stg + m * STRIDE + 256 + lane * 4);
        if (oo < 81) {
          const size_t off = OFF0 + (size_t)(n * 81 + oo) * HW;
          __builtin_nontemporal_store(h0, (f32x4*)(out + off + p0 + lane * 4));
          __builtin_nontemporal_store(h1, (f32x4*)(out + off + p0 + 256 + lane * 4));
        }
      }
    }
    __syncthreads();
  }
}

extern "C" void kernel_launch(void* const* d_in, const int* in_sizes, int n_in,
                              void* d_out, int out_size, void* d_ws, size_t ws_size,
                              hipStream_t stream) {
  const float* x  = (const float*)d_in[0];
  const float* rw = (const float*)d_in[1];
  const float* rb = (const float*)d_in[2];
  const float* nw = (const float*)d_in[3];
  const float* nb = (const float*)d_in[4];
  float* out = (float*)d_out;
  unsigned short* wsA_us = (unsigned short*)d_ws;
  const bf16x8* wsA = (const bf16x8*)d_ws;

  hipLaunchKernelGGL(prep_all, dim3(243), dim3(128), 0, stream, rw, rb, nw, nb, wsA_us);
  hipLaunchKernelGGL(main_kernel, dim3(256), dim3(512), 0, stream, x, wsA, out);
}

// Round 9
// 105.216 us; speedup vs baseline: 2.6471x; 1.0353x over previous
//
#include <hip/hip_runtime.h>

#define HW 16384

typedef short bf16x8 __attribute__((ext_vector_type(8)));
typedef float f32x4 __attribute__((ext_vector_type(4)));

// output offsets (floats): cls_score, cls_score_neg, distances, distances_neg, probs_ori
static constexpr size_t OFF0 = 0;
static constexpr size_t OFF1 = 10616832;   // 8*81*16384
static constexpr size_t OFF2 = 21233664;
static constexpr size_t OFF3 = 31850496;
static constexpr size_t OFF4 = 63700992;   // OFF3 + 3*10616832

#define STRIDE 520                          // floats per staged map row (512 px + 8 pad)

// barrier with LDS-only drain: nt-stores stay in flight across it (no vmcnt(0))
#define BAR()                                                        \
  do {                                                               \
    asm volatile("s_waitcnt lgkmcnt(0)" ::: "memory");               \
    __builtin_amdgcn_sched_barrier(0);                               \
    __builtin_amdgcn_s_barrier();                                    \
    __builtin_amdgcn_sched_barrier(0);                               \
  } while (0)

static __device__ __forceinline__ unsigned short f2bf(float f) {
  unsigned int u = __float_as_uint(f);
  u += 0x7fffu + ((u >> 16) & 1u);   // RNE
  return (unsigned short)(u >> 16);
}

static __device__ __forceinline__ float bflo(unsigned pk) {
  return __uint_as_float(pk << 16);
}
static __device__ __forceinline__ float bfhi(unsigned pk) {
  return __uint_as_float(pk & 0xffff0000u);
}

// write one (row R, channel j) bf16 value into the MFMA A-frag layout
static __device__ __forceinline__ void frag_write(unsigned short* wsA, int R, int j,
                                                  unsigned short v) {
  const int mt = R >> 4;
  const int ks = j >> 5;
  const int hi = (j >> 3) & 3;
  const int jj = j & 7;
  const int lane = hi * 16 + (R & 15);
  wsA[((size_t)((mt * 4 + ks) * 64 + lane)) * 8 + jj] = v;
}

// ---------------- fused prep: reps + full 3-stage chain + norm + frag pack ----------------
__global__ __launch_bounds__(128) void prep_all(const float* __restrict__ rw,
                                                const float* __restrict__ rb,
                                                const float* __restrict__ nw,
                                                const float* __restrict__ nb,
                                                unsigned short* __restrict__ wsA) {
  const int b = blockIdx.x;
  const int k = b / 81, o = b % 81;
  const int j = threadIdx.x;
  __shared__ __align__(16) float hrow[128];
  __shared__ float red[2];

  float v = rw[o * 128 + j] + rb[o * 128 + j];
  float sq = v * v;
#pragma unroll
  for (int m = 1; m < 64; m <<= 1) sq += __shfl_xor(sq, m, 64);
  if ((j & 63) == 0) red[j >> 6] = sq;
  __syncthreads();
  const float r = v / fmaxf(sqrtf(red[0] + red[1]), 1e-12f);
  __syncthreads();
  hrow[j] = r;
  __syncthreads();

  float acc = 0.f;
#pragma unroll
  for (int l = 0; l < 3; ++l) {
    const float4* Wr = (const float4*)(nw + (((size_t)(k * 3 + l)) * 128 + j) * 128);
    const float4* H  = (const float4*)hrow;
    float4 a = {0.f, 0.f, 0.f, 0.f};
#pragma unroll
    for (int q = 0; q < 32; ++q) {
      float4 wv = Wr[q]; float4 hv = H[q];
      a.x = fmaf(wv.x, hv.x, a.x); a.y = fmaf(wv.y, hv.y, a.y);
      a.z = fmaf(wv.z, hv.z, a.z); a.w = fmaf(wv.w, hv.w, a.w);
    }
    acc = (a.x + a.y) + (a.z + a.w) + nb[(k * 3 + l) * 128 + j];
    if (l < 2) acc = fmaxf(acc, 0.f);
    __syncthreads();
    if (l < 2) hrow[j] = acc;
    __syncthreads();
  }

  float sq2 = acc * acc;
#pragma unroll
  for (int m = 1; m < 64; m <<= 1) sq2 += __shfl_xor(sq2, m, 64);
  if ((j & 63) == 0) red[j >> 6] = sq2;
  __syncthreads();
  const float accn = acc / fmaxf(sqrtf(red[0] + red[1]), 1e-12f);

  frag_write(wsA, o * 4 + k + 1, j, f2bf(accn));
  if (k == 0) frag_write(wsA, o * 4, j, f2bf(r));
  if (b == 0) {
#pragma unroll
    for (int R = 324; R < 336; ++R) frag_write(wsA, R, j, (unsigned short)0);
  }
}

// ---------------- main: 512-px tile, 2KB runs, barriers WITHOUT vmcnt drain ----------
// LDS: [0,131072) E tile (512px x 128ch bf16, swizzled) -> reused as staging
//      [131072,139264) ss[4][512]   [139264,141312) invn[512]
__global__ __launch_bounds__(512) void main_kernel(const float* __restrict__ x,
                                                   const bf16x8* __restrict__ wsA,
                                                   float* __restrict__ out) {
  __shared__ __align__(16) char lds[141312];
  float* ss   = (float*)(lds + 131072);
  float* invn = (float*)(lds + 139264);
  float* stg  = (float*)lds;

  const int b = blockIdx.x;
  const int n = b >> 5;
  const int p0 = (b & 31) << 9;      // 512-px chunk
  const int t = threadIdx.x;
  const int lane = t & 63;
  const int w = t >> 6;              // wave 0..7, owns local px [w*64, w*64+64)
  const float* xb = x + ((size_t)n * 128) * HW + p0;

  // ---- build E tile: thread covers px-quad (t&127), channel group (t>>7) ----
  {
    const int pq = (t & 127) * 4;
    const int cg = t >> 7;           // 0..3
    const int swz = (t & 7) << 4;    // ((px>>2)&7)<<4
    float a0 = 0.f, a1 = 0.f, a2 = 0.f, a3 = 0.f;
#pragma unroll
    for (int i = 0; i < 8; ++i) {
      const int c0 = i * 16 + cg * 4;
      float4 v0 = *(const float4*)(xb + (size_t)(c0 + 0) * HW + pq);
      float4 v1 = *(const float4*)(xb + (size_t)(c0 + 1) * HW + pq);
      float4 v2 = *(const float4*)(xb + (size_t)(c0 + 2) * HW + pq);
      float4 v3 = *(const float4*)(xb + (size_t)(c0 + 3) * HW + pq);
      a0 = fmaf(v0.x, v0.x, fmaf(v1.x, v1.x, fmaf(v2.x, v2.x, fmaf(v3.x, v3.x, a0))));
      a1 = fmaf(v0.y, v0.y, fmaf(v1.y, v1.y, fmaf(v2.y, v2.y, fmaf(v3.y, v3.y, a1))));
      a2 = fmaf(v0.z, v0.z, fmaf(v1.z, v1.z, fmaf(v2.z, v2.z, fmaf(v3.z, v3.z, a2))));
      a3 = fmaf(v0.w, v0.w, fmaf(v1.w, v1.w, fmaf(v2.w, v2.w, fmaf(v3.w, v3.w, a3))));
      uint2 wd;
      wd.x = (unsigned)f2bf(v0.x) | ((unsigned)f2bf(v1.x) << 16);
      wd.y = (unsigned)f2bf(v2.x) | ((unsigned)f2bf(v3.x) << 16);
      *(uint2*)(lds + (((pq + 0) * 256 + c0 * 2) ^ swz)) = wd;
      wd.x = (unsigned)f2bf(v0.y) | ((unsigned)f2bf(v1.y) << 16);
      wd.y = (unsigned)f2bf(v2.y) | ((unsigned)f2bf(v3.y) << 16);
      *(uint2*)(lds + (((pq + 1) * 256 + c0 * 2) ^ swz)) = wd;
      wd.x = (unsigned)f2bf(v0.z) | ((unsigned)f2bf(v1.z) << 16);
      wd.y = (unsigned)f2bf(v2.z) | ((unsigned)f2bf(v3.z) << 16);
      *(uint2*)(lds + (((pq + 2) * 256 + c0 * 2) ^ swz)) = wd;
      wd.x = (unsigned)f2bf(v0.w) | ((unsigned)f2bf(v1.w) << 16);
      wd.y = (unsigned)f2bf(v2.w) | ((unsigned)f2bf(v3.w) << 16);
      *(uint2*)(lds + (((pq + 3) * 256 + c0 * 2) ^ swz)) = wd;
    }
    float4 st = {a0, a1, a2, a3};
    *(float4*)&ss[cg * 512 + pq] = st;
  }
  BAR();
  {
    float s = ss[t] + ss[512 + t] + ss[1024 + t] + ss[1536 + t];
    invn[t] = __builtin_amdgcn_rsqf(fmaxf(s, 1e-24f));
  }
  BAR();

  const int og = lane >> 4;
  const int px16 = lane & 15;

  // ---- B-fragments: 4 u-slots (64 px per wave), 64 VGPR ----
  bf16x8 bfrag[4][4];
  float ivp[4];
#pragma unroll
  for (int u = 0; u < 4; ++u) {
    const int p = w * 64 + u * 16 + px16;
    const int swzr = ((p >> 2) & 7) << 4;
#pragma unroll
    for (int ks = 0; ks < 4; ++ks) {
      const int addr = (p * 256 + ks * 64 + (lane >> 4) * 16) ^ swzr;
      bfrag[u][ks] = *(const bf16x8*)(lds + addr);
    }
    ivp[u] = invn[p];
  }
  BAR();   // E consumed (each wave's own ds_reads drained); stg region reusable

  unsigned p01[21], p23[21];

#pragma unroll
  for (int mt = 0; mt < 21; ++mt) {
    bf16x8 afr[4];
#pragma unroll
    for (int ks = 0; ks < 4; ++ks) afr[ks] = wsA[(mt * 4 + ks) * 64 + lane];
    f32x4 cc[4];
#pragma unroll
    for (int u = 0; u < 4; ++u) cc[u] = (f32x4){0.f, 0.f, 0.f, 0.f};
#pragma unroll
    for (int ks = 0; ks < 4; ++ks) {
#pragma unroll
      for (int u = 0; u < 4; ++u)
        cc[u] = __builtin_amdgcn_mfma_f32_16x16x32_bf16(afr[ks], bfrag[u][ks], cc[u], 0, 0, 0);
    }
    const int o = mt * 4 + og;
    const bool valid = (o < 81);
    float pr_[4];
#pragma unroll
    for (int u = 0; u < 4; ++u) {
      const f32x4 c = cc[u];
      const float iv = ivp[u];
      float q0 = fmaxf(2.f - 2.f * (c[0] * iv), 0.f);
      float q1 = fmaxf(2.f - 2.f * (c[1] * iv), 0.f);
      float q2 = fmaxf(2.f - 2.f * (c[2] * iv), 0.f);
      float q3 = fmaxf(2.f - 2.f * (c[3] * iv), 0.f);
      float d0 = __builtin_amdgcn_sqrtf(q0);
      float d1 = __builtin_amdgcn_sqrtf(q1);
      float d2 = __builtin_amdgcn_sqrtf(q2);
      float d3 = __builtin_amdgcn_sqrtf(q3);
      float qmin = fminf(q1, fminf(q2, q3));
      float dmin = fminf(d1, fminf(d2, d3));
      float pneg = __expf(-2.f * qmin);
      float pori = __expf(-2.f * q0);
      float tt = d0 + 0.3f * fmaxf(2.f - dmin, 0.f);
      float pr = __expf(-2.f * tt * tt);
      pr_[u] = valid ? pr : 0.f;
      float* su = stg + og * 6 * STRIDE + w * 64 + u * 16 + px16;
      su[0 * STRIDE] = d0;
      su[1 * STRIDE] = d1;
      su[2 * STRIDE] = d2;
      su[3 * STRIDE] = d3;
      su[4 * STRIDE] = pneg;
      su[5 * STRIDE] = pori;
    }
    p01[mt] = ((unsigned)f2bf(pr_[1]) << 16) | (unsigned)f2bf(pr_[0]);
    p23[mt] = ((unsigned)f2bf(pr_[3]) << 16) | (unsigned)f2bf(pr_[2]);
    BAR();
    // writeout: wave owns 3 maps; per map, 2 back-to-back f32x4 = monotone 2KB run
#pragma unroll
    for (int r = 0; r < 3; ++r) {
      const int m = w * 3 + r;          // 0..23
      const int ogm = m / 6, jv = m % 6;
      const int oo = mt * 4 + ogm;
      f32x4 h0 = *(const f32x4*)(stg + m * STRIDE + lane * 4);
      f32x4 h1 = *(const f32x4*)(stg + m * STRIDE + 256 + lane * 4);
      if (oo < 81) {
        const size_t idx81 = (size_t)(n * 81 + oo);
        size_t off;
        if (jv == 0) off = OFF2 + idx81 * HW;
        else if (jv <= 3) off = OFF3 + (idx81 * 3 + (jv - 1)) * HW;
        else if (jv == 4) off = OFF1 + idx81 * HW;
        else off = OFF4 + idx81 * HW;
        __builtin_nontemporal_store(h0, (f32x4*)(out + off + p0 + lane * 4));
        __builtin_nontemporal_store(h1, (f32x4*)(out + off + p0 + 256 + lane * 4));
      }
    }
    BAR();
  }

  // ---- cls_score: per-px sum over all o (in-lane over mt, shfl over og) ----
  float s0 = 0.f, s1 = 0.f, s2 = 0.f, s3 = 0.f;
#pragma unroll
  for (int mt = 0; mt < 21; ++mt) {
    s0 += bflo(p01[mt]); s1 += bfhi(p01[mt]);
    s2 += bflo(p23[mt]); s3 += bfhi(p23[mt]);
  }
  s0 += __shfl_xor(s0, 16, 64); s0 += __shfl_xor(s0, 32, 64);
  s1 += __shfl_xor(s1, 16, 64); s1 += __shfl_xor(s1, 32, 64);
  s2 += __shfl_xor(s2, 16, 64); s2 += __shfl_xor(s2, 32, 64);
  s3 += __shfl_xor(s3, 16, 64); s3 += __shfl_xor(s3, 32, 64);
  const float is0 = __builtin_amdgcn_rcpf(s0);
  const float is1 = __builtin_amdgcn_rcpf(s1);
  const float is2 = __builtin_amdgcn_rcpf(s2);
  const float is3 = __builtin_amdgcn_rcpf(s3);

#pragma unroll
  for (int g = 0; g < 6; ++g) {
    const int nmt = (g < 5) ? 4 : 1;
#pragma unroll
    for (int mtl = 0; mtl < 4; ++mtl) {
      if (mtl < nmt) {
        const int mt = g * 4 + mtl;
        float* su = stg + (mtl * 4 + og) * STRIDE + w * 64 + px16;
        su[0]  = bflo(p01[mt]) * is0;
        su[16] = bfhi(p01[mt]) * is1;
        su[32] = bflo(p23[mt]) * is2;
        su[48] = bfhi(p23[mt]) * is3;
      }
    }
    BAR();
    const int nrows = nmt * 4;
#pragma unroll
    for (int r = 0; r < 2; ++r) {
      const int m = w * 2 + r;          // 0..15
      if (m < nrows) {
        const int mtl = m >> 2, ogm = m & 3;
        const int oo = (g * 4 + mtl) * 4 + ogm;
        f32x4 h0 = *(const f32x4*)(stg + m * STRIDE + lane * 4);
        f32x4 h1 = *(const f32x4*)(stg + m * STRIDE + 256 + lane * 4);
        if (oo < 81) {
          const size_t off = OFF0 + (size_t)(n * 81 + oo) * HW;
          __builtin_nontemporal_store(h0, (f32x4*)(out + off + p0 + lane * 4));
          __builtin_nontemporal_store(h1, (f32x4*)(out + off + p0 + 256 + lane * 4));
        }
      }
    }
    BAR();
  }
}

extern "C" void kernel_launch(void* const* d_in, const int* in_sizes, int n_in,
                              void* d_out, int out_size, void* d_ws, size_t ws_size,
                              hipStream_t stream) {
  const float* x  = (const float*)d_in[0];
  const float* rw = (const float*)d_in[1];
  const float* rb = (const float*)d_in[2];
  const float* nw = (const float*)d_in[3];
  const float* nb = (const float*)d_in[4];
  float* out = (float*)d_out;
  unsigned short* wsA_us = (unsigned short*)d_ws;
  const bf16x8* wsA = (const bf16x8*)d_ws;

  hipLaunchKernelGGL(prep_all, dim3(243), dim3(128), 0, stream, rw, rb, nw, nb, wsA_us);
  hipLaunchKernelGGL(main_kernel, dim3(256), dim3(512), 0, stream, x, wsA, out);
}

// Round 10
// 101.027 us; speedup vs baseline: 2.7569x; 1.0415x over previous
//
#include <hip/hip_runtime.h>

#define HW 16384

typedef short bf16x8 __attribute__((ext_vector_type(8)));
typedef float f32x4 __attribute__((ext_vector_type(4)));

// output offsets (floats): cls_score, cls_score_neg, distances, distances_neg, probs_ori
static constexpr size_t OFF0 = 0;
static constexpr size_t OFF1 = 10616832;   // 8*81*16384
static constexpr size_t OFF2 = 21233664;
static constexpr size_t OFF3 = 31850496;
static constexpr size_t OFF4 = 63700992;   // OFF3 + 3*10616832

#define STRIDE 520                          // floats per staged map row (512 px + 8 pad)
#define STG1_OFF 50176                      // bytes; 24*520*4 = 49920 rounded up, 16-aligned

// barrier with LDS-only drain: nt-stores stay in flight across it (no vmcnt(0))
#define BAR()                                                        \
  do {                                                               \
    asm volatile("s_waitcnt lgkmcnt(0)" ::: "memory");               \
    __builtin_amdgcn_sched_barrier(0);                               \
    __builtin_amdgcn_s_barrier();                                    \
    __builtin_amdgcn_sched_barrier(0);                               \
  } while (0)

static __device__ __forceinline__ unsigned short f2bf(float f) {
  unsigned int u = __float_as_uint(f);
  u += 0x7fffu + ((u >> 16) & 1u);   // RNE
  return (unsigned short)(u >> 16);
}

static __device__ __forceinline__ float bflo(unsigned pk) {
  return __uint_as_float(pk << 16);
}
static __device__ __forceinline__ float bfhi(unsigned pk) {
  return __uint_as_float(pk & 0xffff0000u);
}

// write one (row R, channel j) bf16 value into the MFMA A-frag layout
static __device__ __forceinline__ void frag_write(unsigned short* wsA, int R, int j,
                                                  unsigned short v) {
  const int mt = R >> 4;
  const int ks = j >> 5;
  const int hi = (j >> 3) & 3;
  const int jj = j & 7;
  const int lane = hi * 16 + (R & 15);
  wsA[((size_t)((mt * 4 + ks) * 64 + lane)) * 8 + jj] = v;
}

// ---------------- fused prep: reps + full 3-stage chain + norm + frag pack ----------------
__global__ __launch_bounds__(128) void prep_all(const float* __restrict__ rw,
                                                const float* __restrict__ rb,
                                                const float* __restrict__ nw,
                                                const float* __restrict__ nb,
                                                unsigned short* __restrict__ wsA) {
  const int b = blockIdx.x;
  const int k = b / 81, o = b % 81;
  const int j = threadIdx.x;
  __shared__ __align__(16) float hrow[128];
  __shared__ float red[2];

  float v = rw[o * 128 + j] + rb[o * 128 + j];
  float sq = v * v;
#pragma unroll
  for (int m = 1; m < 64; m <<= 1) sq += __shfl_xor(sq, m, 64);
  if ((j & 63) == 0) red[j >> 6] = sq;
  __syncthreads();
  const float r = v / fmaxf(sqrtf(red[0] + red[1]), 1e-12f);
  __syncthreads();
  hrow[j] = r;
  __syncthreads();

  float acc = 0.f;
#pragma unroll
  for (int l = 0; l < 3; ++l) {
    const float4* Wr = (const float4*)(nw + (((size_t)(k * 3 + l)) * 128 + j) * 128);
    const float4* H  = (const float4*)hrow;
    float4 a = {0.f, 0.f, 0.f, 0.f};
#pragma unroll
    for (int q = 0; q < 32; ++q) {
      float4 wv = Wr[q]; float4 hv = H[q];
      a.x = fmaf(wv.x, hv.x, a.x); a.y = fmaf(wv.y, hv.y, a.y);
      a.z = fmaf(wv.z, hv.z, a.z); a.w = fmaf(wv.w, hv.w, a.w);
    }
    acc = (a.x + a.y) + (a.z + a.w) + nb[(k * 3 + l) * 128 + j];
    if (l < 2) acc = fmaxf(acc, 0.f);
    __syncthreads();
    if (l < 2) hrow[j] = acc;
    __syncthreads();
  }

  float sq2 = acc * acc;
#pragma unroll
  for (int m = 1; m < 64; m <<= 1) sq2 += __shfl_xor(sq2, m, 64);
  if ((j & 63) == 0) red[j >> 6] = sq2;
  __syncthreads();
  const float accn = acc / fmaxf(sqrtf(red[0] + red[1]), 1e-12f);

  frag_write(wsA, o * 4 + k + 1, j, f2bf(accn));
  if (k == 0) frag_write(wsA, o * 4, j, f2bf(r));
  if (b == 0) {
#pragma unroll
    for (int R = 324; R < 336; ++R) frag_write(wsA, R, j, (unsigned short)0);
  }
}

// -------- main: 512-px tile, 2KB runs, DOUBLE-BUFFERED staging, 1 barrier/iter --------
// LDS: [0,131072) E tile (512px x 128ch bf16, swizzled) -> reused as stg0/stg1
//      [131072,139264) ss[4][512]   [139264,141312) invn[512]
__global__ __launch_bounds__(512) void main_kernel(const float* __restrict__ x,
                                                   const bf16x8* __restrict__ wsA,
                                                   float* __restrict__ out) {
  __shared__ __align__(16) char lds[141312];
  float* ss   = (float*)(lds + 131072);
  float* invn = (float*)(lds + 139264);
  float* stg0 = (float*)lds;
  float* stg1 = (float*)(lds + STG1_OFF);

  const int b = blockIdx.x;
  const int n = b >> 5;
  const int p0 = (b & 31) << 9;      // 512-px chunk
  const int t = threadIdx.x;
  const int lane = t & 63;
  const int w = t >> 6;              // wave 0..7, owns local px [w*64, w*64+64)
  const float* xb = x + ((size_t)n * 128) * HW + p0;

  // ---- build E tile: thread covers px-quad (t&127), channel group (t>>7) ----
  {
    const int pq = (t & 127) * 4;
    const int cg = t >> 7;           // 0..3
    const int swz = (t & 7) << 4;    // ((px>>2)&7)<<4
    float a0 = 0.f, a1 = 0.f, a2 = 0.f, a3 = 0.f;
#pragma unroll
    for (int i = 0; i < 8; ++i) {
      const int c0 = i * 16 + cg * 4;
      float4 v0 = *(const float4*)(xb + (size_t)(c0 + 0) * HW + pq);
      float4 v1 = *(const float4*)(xb + (size_t)(c0 + 1) * HW + pq);
      float4 v2 = *(const float4*)(xb + (size_t)(c0 + 2) * HW + pq);
      float4 v3 = *(const float4*)(xb + (size_t)(c0 + 3) * HW + pq);
      a0 = fmaf(v0.x, v0.x, fmaf(v1.x, v1.x, fmaf(v2.x, v2.x, fmaf(v3.x, v3.x, a0))));
      a1 = fmaf(v0.y, v0.y, fmaf(v1.y, v1.y, fmaf(v2.y, v2.y, fmaf(v3.y, v3.y, a1))));
      a2 = fmaf(v0.z, v0.z, fmaf(v1.z, v1.z, fmaf(v2.z, v2.z, fmaf(v3.z, v3.z, a2))));
      a3 = fmaf(v0.w, v0.w, fmaf(v1.w, v1.w, fmaf(v2.w, v2.w, fmaf(v3.w, v3.w, a3))));
      uint2 wd;
      wd.x = (unsigned)f2bf(v0.x) | ((unsigned)f2bf(v1.x) << 16);
      wd.y = (unsigned)f2bf(v2.x) | ((unsigned)f2bf(v3.x) << 16);
      *(uint2*)(lds + (((pq + 0) * 256 + c0 * 2) ^ swz)) = wd;
      wd.x = (unsigned)f2bf(v0.y) | ((unsigned)f2bf(v1.y) << 16);
      wd.y = (unsigned)f2bf(v2.y) | ((unsigned)f2bf(v3.y) << 16);
      *(uint2*)(lds + (((pq + 1) * 256 + c0 * 2) ^ swz)) = wd;
      wd.x = (unsigned)f2bf(v0.z) | ((unsigned)f2bf(v1.z) << 16);
      wd.y = (unsigned)f2bf(v2.z) | ((unsigned)f2bf(v3.z) << 16);
      *(uint2*)(lds + (((pq + 2) * 256 + c0 * 2) ^ swz)) = wd;
      wd.x = (unsigned)f2bf(v0.w) | ((unsigned)f2bf(v1.w) << 16);
      wd.y = (unsigned)f2bf(v2.w) | ((unsigned)f2bf(v3.w) << 16);
      *(uint2*)(lds + (((pq + 3) * 256 + c0 * 2) ^ swz)) = wd;
    }
    float4 st = {a0, a1, a2, a3};
    *(float4*)&ss[cg * 512 + pq] = st;
  }
  BAR();
  {
    float s = ss[t] + ss[512 + t] + ss[1024 + t] + ss[1536 + t];
    invn[t] = __builtin_amdgcn_rsqf(fmaxf(s, 1e-24f));
  }
  BAR();

  const int og = lane >> 4;
  const int px16 = lane & 15;

  // ---- B-fragments: 4 u-slots (64 px per wave), 64 VGPR ----
  bf16x8 bfrag[4][4];
  float ivp[4];
#pragma unroll
  for (int u = 0; u < 4; ++u) {
    const int p = w * 64 + u * 16 + px16;
    const int swzr = ((p >> 2) & 7) << 4;
#pragma unroll
    for (int ks = 0; ks < 4; ++ks) {
      const int addr = (p * 256 + ks * 64 + (lane >> 4) * 16) ^ swzr;
      bfrag[u][ks] = *(const bf16x8*)(lds + addr);
    }
    ivp[u] = invn[p];
  }
  BAR();   // E consumed; stg0/stg1 region reusable

  unsigned p01[21], p23[21];

#pragma unroll
  for (int mt = 0; mt < 21; ++mt) {
    float* sb = (mt & 1) ? stg1 : stg0;
    bf16x8 afr[4];
#pragma unroll
    for (int ks = 0; ks < 4; ++ks) afr[ks] = wsA[(mt * 4 + ks) * 64 + lane];
    f32x4 cc[4];
#pragma unroll
    for (int u = 0; u < 4; ++u) cc[u] = (f32x4){0.f, 0.f, 0.f, 0.f};
#pragma unroll
    for (int ks = 0; ks < 4; ++ks) {
#pragma unroll
      for (int u = 0; u < 4; ++u)
        cc[u] = __builtin_amdgcn_mfma_f32_16x16x32_bf16(afr[ks], bfrag[u][ks], cc[u], 0, 0, 0);
    }
    const int o = mt * 4 + og;
    const bool valid = (o < 81);
    float pr_[4];
#pragma unroll
    for (int u = 0; u < 4; ++u) {
      const f32x4 c = cc[u];
      const float iv = ivp[u];
      float q0 = fmaxf(2.f - 2.f * (c[0] * iv), 0.f);
      float q1 = fmaxf(2.f - 2.f * (c[1] * iv), 0.f);
      float q2 = fmaxf(2.f - 2.f * (c[2] * iv), 0.f);
      float q3 = fmaxf(2.f - 2.f * (c[3] * iv), 0.f);
      float d0 = __builtin_amdgcn_sqrtf(q0);
      float d1 = __builtin_amdgcn_sqrtf(q1);
      float d2 = __builtin_amdgcn_sqrtf(q2);
      float d3 = __builtin_amdgcn_sqrtf(q3);
      float qmin = fminf(q1, fminf(q2, q3));
      float dmin = fminf(d1, fminf(d2, d3));
      float pneg = __expf(-2.f * qmin);
      float pori = __expf(-2.f * q0);
      float tt = d0 + 0.3f * fmaxf(2.f - dmin, 0.f);
      float pr = __expf(-2.f * tt * tt);
      pr_[u] = valid ? pr : 0.f;
      float* su = sb + og * 6 * STRIDE + w * 64 + u * 16 + px16;
      su[0 * STRIDE] = d0;
      su[1 * STRIDE] = d1;
      su[2 * STRIDE] = d2;
      su[3 * STRIDE] = d3;
      su[4 * STRIDE] = pneg;
      su[5 * STRIDE] = pori;
    }
    p01[mt] = ((unsigned)f2bf(pr_[1]) << 16) | (unsigned)f2bf(pr_[0]);
    p23[mt] = ((unsigned)f2bf(pr_[3]) << 16) | (unsigned)f2bf(pr_[2]);
    BAR();   // single barrier per iteration (dbuf makes trailing barrier unnecessary)
    // writeout: wave owns 3 maps; per map, 2 back-to-back f32x4 = monotone 2KB run
#pragma unroll
    for (int r = 0; r < 3; ++r) {
      const int m = w * 3 + r;          // 0..23
      const int ogm = m / 6, jv = m % 6;
      const int oo = mt * 4 + ogm;
      f32x4 h0 = *(const f32x4*)(sb + m * STRIDE + lane * 4);
      f32x4 h1 = *(const f32x4*)(sb + m * STRIDE + 256 + lane * 4);
      if (oo < 81) {
        const size_t idx81 = (size_t)(n * 81 + oo);
        size_t off;
        if (jv == 0) off = OFF2 + idx81 * HW;
        else if (jv <= 3) off = OFF3 + (idx81 * 3 + (jv - 1)) * HW;
        else if (jv == 4) off = OFF1 + idx81 * HW;
        else off = OFF4 + idx81 * HW;
        __builtin_nontemporal_store(h0, (f32x4*)(out + off + p0 + lane * 4));
        __builtin_nontemporal_store(h1, (f32x4*)(out + off + p0 + 256 + lane * 4));
      }
    }
  }

  // ---- cls_score: per-px sum over all o (in-lane over mt, shfl over og) ----
  float s0 = 0.f, s1 = 0.f, s2 = 0.f, s3 = 0.f;
#pragma unroll
  for (int mt = 0; mt < 21; ++mt) {
    s0 += bflo(p01[mt]); s1 += bfhi(p01[mt]);
    s2 += bflo(p23[mt]); s3 += bfhi(p23[mt]);
  }
  s0 += __shfl_xor(s0, 16, 64); s0 += __shfl_xor(s0, 32, 64);
  s1 += __shfl_xor(s1, 16, 64); s1 += __shfl_xor(s1, 32, 64);
  s2 += __shfl_xor(s2, 16, 64); s2 += __shfl_xor(s2, 32, 64);
  s3 += __shfl_xor(s3, 16, 64); s3 += __shfl_xor(s3, 32, 64);
  const float is0 = __builtin_amdgcn_rcpf(s0);
  const float is1 = __builtin_amdgcn_rcpf(s1);
  const float is2 = __builtin_amdgcn_rcpf(s2);
  const float is3 = __builtin_amdgcn_rcpf(s3);

  // g-parity offset by 1 so g=0 stages into stg1 (mt=20's writeout read stg0)
#pragma unroll
  for (int g = 0; g < 6; ++g) {
    float* sb = ((g + 1) & 1) ? stg1 : stg0;
    const int nmt = (g < 5) ? 4 : 1;
#pragma unroll
    for (int mtl = 0; mtl < 4; ++mtl) {
      if (mtl < nmt) {
        const int mt = g * 4 + mtl;
        float* su = sb + (mtl * 4 + og) * STRIDE + w * 64 + px16;
        su[0]  = bflo(p01[mt]) * is0;
        su[16] = bfhi(p01[mt]) * is1;
        su[32] = bflo(p23[mt]) * is2;
        su[48] = bfhi(p23[mt]) * is3;
      }
    }
    BAR();
    const int nrows = nmt * 4;
#pragma unroll
    for (int r = 0; r < 2; ++r) {
      const int m = w * 2 + r;          // 0..15
      if (m < nrows) {
        const int mtl = m >> 2, ogm = m & 3;
        const int oo = (g * 4 + mtl) * 4 + ogm;
        f32x4 h0 = *(const f32x4*)(sb + m * STRIDE + lane * 4);
        f32x4 h1 = *(const f32x4*)(sb + m * STRIDE + 256 + lane * 4);
        if (oo < 81) {
          const size_t off = OFF0 + (size_t)(n * 81 + oo) * HW;
          __builtin_nontemporal_store(h0, (f32x4*)(out + off + p0 + lane * 4));
          __builtin_nontemporal_store(h1, (f32x4*)(out + off + p0 + 256 + lane * 4));
        }
      }
    }
  }
}

extern "C" void kernel_launch(void* const* d_in, const int* in_sizes, int n_in,
                              void* d_out, int out_size, void* d_ws, size_t ws_size,
                              hipStream_t stream) {
  const float* x  = (const float*)d_in[0];
  const float* rw = (const float*)d_in[1];
  const float* rb = (const float*)d_in[2];
  const float* nw = (const float*)d_in[3];
  const float* nb = (const float*)d_in[4];
  float* out = (float*)d_out;
  unsigned short* wsA_us = (unsigned short*)d_ws;
  const bf16x8* wsA = (const bf16x8*)d_ws;

  hipLaunchKernelGGL(prep_all, dim3(243), dim3(128), 0, stream, rw, rb, nw, nb, wsA_us);
  hipLaunchKernelGGL(main_kernel, dim3(256), dim3(512), 0, stream, x, wsA, out);
}